// Round 18
// baseline (806.934 us; speedup 1.0000x reference)
//
#include <hip/hip_runtime.h>
#include <math.h>

#define HD 128
#define FD 128
#define RD 64
#define TE 128          // edges per tile
#define RC_CUT 5.0f

typedef _Float16 half8_t __attribute__((ext_vector_type(8)));
typedef _Float16 half4_t __attribute__((ext_vector_type(4)));
typedef float floatx4 __attribute__((ext_vector_type(4)));

__device__ __forceinline__ float fast_tanh(float x) {
    float ex = __expf(2.0f * x);
    return 1.0f - 2.0f / (ex + 1.0f);
}

// ---------------- lin1: h = x @ lin1_w.T  (h stored f16) ----------------
__global__ __launch_bounds__(256) void lin1_kernel(const float* __restrict__ x,
                                                   const float* __restrict__ w,
                                                   _Float16* __restrict__ h, int n)
{
    __shared__ float sx[16][HD];
    int base = blockIdx.x * 16;
    for (int i = threadIdx.x; i < 16 * HD; i += 256) {
        int r = i >> 7, c = i & 127;
        int row = base + r;
        sx[r][c] = (row < n) ? x[(size_t)row * HD + c] : 0.0f;
    }
    __syncthreads();
    int f = threadIdx.x & 127;
    int half = threadIdx.x >> 7;
    float acc[8];
#pragma unroll
    for (int r = 0; r < 8; ++r) acc[r] = 0.0f;
    const float* wrow = w + (size_t)f * HD;
    for (int k = 0; k < HD; k += 4) {
        float4 wv = *(const float4*)(wrow + k);
#pragma unroll
        for (int r = 0; r < 8; ++r) {
            acc[r] += sx[half * 8 + r][k]     * wv.x;
            acc[r] += sx[half * 8 + r][k + 1] * wv.y;
            acc[r] += sx[half * 8 + r][k + 2] * wv.z;
            acc[r] += sx[half * 8 + r][k + 3] * wv.w;
        }
    }
#pragma unroll
    for (int r = 0; r < 8; ++r) {
        int row = base + half * 8 + r;
        if (row < n) h[(size_t)row * FD + f] = (_Float16)acc[r];
    }
}

// ---------------- bucketing by dst: count / 3-level scan / scatter ----------
__global__ __launch_bounds__(256) void count_kernel(const int* __restrict__ dstp,
                                                    int* cnt, int E)
{
    for (int e = blockIdx.x * blockDim.x + threadIdx.x; e < E;
         e += gridDim.x * blockDim.x)
        atomicAdd(&cnt[dstp[e]], 1);
}

__global__ __launch_bounds__(256) void scan1_kernel(const int* __restrict__ cnt,
                                                    int* bsum, int n)
{
    int i = blockIdx.x * 256 + threadIdx.x;
    int v = (i < n) ? cnt[i] : 0;
    int lane = threadIdx.x & 63;
    int wv = threadIdx.x >> 6;
    int s = v;
#pragma unroll
    for (int d = 1; d < 64; d <<= 1) s += __shfl_xor(s, d);
    __shared__ int ws[4];
    if (lane == 0) ws[wv] = s;
    __syncthreads();
    if (threadIdx.x == 0) bsum[blockIdx.x] = ws[0] + ws[1] + ws[2] + ws[3];
}

__global__ void scan2_kernel(int* bsum, int nb, int* totalp)
{
    int lane = threadIdx.x;
    int carry = 0;
    for (int base = 0; base < nb; base += 64) {
        int i = base + lane;
        int v = (i < nb) ? bsum[i] : 0;
        int orig = v;
#pragma unroll
        for (int d = 1; d < 64; d <<= 1) {
            int t = __shfl_up(v, d);
            if (lane >= d) v += t;
        }
        if (i < nb) bsum[i] = carry + v - orig;
        carry += __shfl(v, 63);
    }
    if (lane == 0) *totalp = carry;
}

__global__ __launch_bounds__(256) void scan3_kernel(int* cnt, const int* __restrict__ bsum,
                                                    int* offs, int n)
{
    int i = blockIdx.x * 256 + threadIdx.x;
    int v = (i < n) ? cnt[i] : 0;
    int lane = threadIdx.x & 63;
    int wv = threadIdx.x >> 6;
    int incl = v;
#pragma unroll
    for (int d = 1; d < 64; d <<= 1) {
        int t = __shfl_up(incl, d);
        if (lane >= d) incl += t;
    }
    __shared__ int ws[4];
    if (lane == 63) ws[wv] = incl;
    __syncthreads();
    int wbase = 0;
#pragma unroll
    for (int w = 0; w < 4; ++w) wbase += (w < wv) ? ws[w] : 0;
    int excl = bsum[blockIdx.x] + wbase + incl - v;
    if (i < n) { offs[i] = excl; cnt[i] = excl; }   // cnt becomes scatter cursor
}

// inv[e] = permuted position; meta[pos] = src | (dst << 16)  (n < 65536)
__global__ __launch_bounds__(256) void scatter_kernel(
    const int* __restrict__ srcp, const int* __restrict__ dstp,
    int* cursor, int* __restrict__ inv, unsigned int* __restrict__ meta, int E)
{
    for (int e = blockIdx.x * blockDim.x + threadIdx.x; e < E;
         e += gridDim.x * blockDim.x) {
        int d = dstp[e];
        int p = atomicAdd(&cursor[d], 1);
        inv[e] = p;
        meta[p] = (unsigned int)srcp[e] | ((unsigned int)d << 16);
    }
}

// ---------------- shared LDS helpers ----------------
__device__ __forceinline__ half8_t lds_read8(const char* base, int row,
                                             int rowstride, int col) {
    int off = row * rowstride + ((col * 2) ^ ((row & 7) << 4));
    return *(const half8_t*)(base + off);
}

// ==================== PHASE A: filter GEMMs, natural edge order ==============
// R8/R9 structure (proven 353 us): swapped MFMA, half4 direct store of
// W = C*(filter) to Wp[inv[e]]; NO h access here (R10: mixing the h gather
// with the Wp write-combine stream doubles write traffic).
// R18: edge_weight/inv loads HOISTED to tile top (4 VGPRs live across the
// GEMMs) so their ~400-600 cyc L2 latency hides under GEMM1+tanh+GEMM2
// instead of being exposed serially in the epilogue.
__global__ __launch_bounds__(1024, 8) void edge_gemm_kernel(
    const float* __restrict__ edge_weight,
    const float* __restrict__ edge_attr,
    const float* __restrict__ fw1, const float* __restrict__ fb1,
    const float* __restrict__ fw2, const float* __restrict__ fb2,
    const int* __restrict__ inv,
    _Float16* __restrict__ Wp,
    int E, int ntiles)
{
    extern __shared__ char smem[];
    char* sT  = smem;
    char* sB1 = smem + 32768;
    char* sB2 = smem + 49152;

    // ---- stage weights once per block (fp32 -> f16, swizzled) ----
    for (int i = threadIdx.x * 8; i < FD * RD; i += blockDim.x * 8) {
        int r = i >> 6, c = i & 63;
        const float4* g = (const float4*)(fw1 + (size_t)r * RD + c);
        float4 v0 = g[0], v1 = g[1];
        half8_t hv;
        hv[0] = (_Float16)v0.x; hv[1] = (_Float16)v0.y;
        hv[2] = (_Float16)v0.z; hv[3] = (_Float16)v0.w;
        hv[4] = (_Float16)v1.x; hv[5] = (_Float16)v1.y;
        hv[6] = (_Float16)v1.z; hv[7] = (_Float16)v1.w;
        *(half8_t*)(sB1 + r * 128 + ((c * 2) ^ ((r & 7) << 4))) = hv;
    }
    for (int i = threadIdx.x * 8; i < FD * FD; i += blockDim.x * 8) {
        int r = i >> 7, c = i & 127;
        const float4* g = (const float4*)(fw2 + (size_t)r * FD + c);
        float4 v0 = g[0], v1 = g[1];
        half8_t hv;
        hv[0] = (_Float16)v0.x; hv[1] = (_Float16)v0.y;
        hv[2] = (_Float16)v0.z; hv[3] = (_Float16)v0.w;
        hv[4] = (_Float16)v1.x; hv[5] = (_Float16)v1.y;
        hv[6] = (_Float16)v1.z; hv[7] = (_Float16)v1.w;
        *(half8_t*)(sB2 + r * 256 + ((c * 2) ^ ((r & 7) << 4))) = hv;
    }

    int lane = threadIdx.x & 63;
    int wid  = threadIdx.x >> 6;   // 0..15
    int wm = wid >> 2;             // 0..3  (edge dim, 32 each)
    int wn = wid & 3;              // 0..3  (filter dim, 32 each)
    int l15 = lane & 15;
    int l4  = lane >> 4;

    // swapped-fragment f-base per (ni): 4 consecutive f columns
    int fbase[2];
#pragma unroll
    for (int ni = 0; ni < 2; ++ni) fbase[ni] = wn * 32 + ni * 16 + l4 * 4;

    // prefetch lane mapping: thread -> (row, col8) of the 128x64 A tile
    int pr = threadIdx.x >> 3;          // 0..127
    int pc = (threadIdx.x & 7) * 8;     // 0..56

    // ---- prologue: prefetch first tile's A into registers ----
    float4 pA0 = {0.f, 0.f, 0.f, 0.f}, pA1 = {0.f, 0.f, 0.f, 0.f};
    {
        int e = blockIdx.x * TE + pr;
        if (e < E) {
            const float4* g = (const float4*)(edge_attr + (size_t)e * RD + pc);
            pA0 = g[0]; pA1 = g[1];
        }
    }
    __syncthreads();   // weights staged

    for (int tile = blockIdx.x; tile < ntiles; tile += gridDim.x) {
        int e0 = tile * TE;
        // ---- stage A from prefetch registers (cvt + ds_write only) ----
        {
            half8_t hv;
            hv[0] = (_Float16)pA0.x; hv[1] = (_Float16)pA0.y;
            hv[2] = (_Float16)pA0.z; hv[3] = (_Float16)pA0.w;
            hv[4] = (_Float16)pA1.x; hv[5] = (_Float16)pA1.y;
            hv[6] = (_Float16)pA1.z; hv[7] = (_Float16)pA1.w;
            *(half8_t*)(sT + pr * 128 + ((pc * 2) ^ ((pr & 7) << 4))) = hv;
        }

        // ---- R18 hoist: epilogue metadata loads issued HERE; latency
        //      hides under GEMM1+tanh+GEMM2 (4 VGPRs live) ----
        float dmt[2];
        int   pvt[2];
#pragma unroll
        for (int mi = 0; mi < 2; ++mi) {
            int el = wm * 32 + mi * 16 + l15;
            int ge = e0 + el;
            int idx = (ge < E) ? ge : (E - 1);
            dmt[mi] = edge_weight[idx];
            pvt[mi] = inv[idx];
        }
        __syncthreads();

        // ---- GEMM1 (swapped): accT[f-frag][e-col] ----
        floatx4 acc[2][2];
#pragma unroll
        for (int mi = 0; mi < 2; ++mi)
#pragma unroll
            for (int ni = 0; ni < 2; ++ni)
                acc[mi][ni] = (floatx4){0.f, 0.f, 0.f, 0.f};
#pragma unroll
        for (int ks = 0; ks < 2; ++ks) {
            int k = ks * 32 + l4 * 8;
            half8_t a[2], b[2];
#pragma unroll
            for (int mi = 0; mi < 2; ++mi)
                a[mi] = lds_read8(sT, wm * 32 + mi * 16 + l15, 128, k);
#pragma unroll
            for (int ni = 0; ni < 2; ++ni)
                b[ni] = lds_read8(sB1, wn * 32 + ni * 16 + l15, 128, k);
#pragma unroll
            for (int mi = 0; mi < 2; ++mi)
#pragma unroll
                for (int ni = 0; ni < 2; ++ni)
                    acc[mi][ni] = __builtin_amdgcn_mfma_f32_16x16x32_f16(
                        b[ni], a[mi], acc[mi][ni], 0, 0, 0);
        }
        __syncthreads();

        // ---- bias + tanh -> T (one ds_write_b64 per fragment) ----
#pragma unroll
        for (int ni = 0; ni < 2; ++ni) {
            float4 bv = *(const float4*)(fb1 + fbase[ni]);
#pragma unroll
            for (int mi = 0; mi < 2; ++mi) {
                int e = wm * 32 + mi * 16 + l15;
                half4_t hv;
                hv[0] = (_Float16)fast_tanh(acc[mi][ni][0] + bv.x);
                hv[1] = (_Float16)fast_tanh(acc[mi][ni][1] + bv.y);
                hv[2] = (_Float16)fast_tanh(acc[mi][ni][2] + bv.z);
                hv[3] = (_Float16)fast_tanh(acc[mi][ni][3] + bv.w);
                *(half4_t*)(sT + e * 256 + ((fbase[ni] * 2) ^ ((e & 7) << 4))) = hv;
            }
        }
        __syncthreads();

        // ---- GEMM2 (swapped): accT2[f-frag][e-col] ----
        floatx4 acc2[2][2];
#pragma unroll
        for (int mi = 0; mi < 2; ++mi)
#pragma unroll
            for (int ni = 0; ni < 2; ++ni)
                acc2[mi][ni] = (floatx4){0.f, 0.f, 0.f, 0.f};
#pragma unroll
        for (int ks = 0; ks < 4; ++ks) {
            int k = ks * 32 + l4 * 8;
            half8_t a[2], b[2];
#pragma unroll
            for (int mi = 0; mi < 2; ++mi)
                a[mi] = lds_read8(sT, wm * 32 + mi * 16 + l15, 256, k);
#pragma unroll
            for (int ni = 0; ni < 2; ++ni)
                b[ni] = lds_read8(sB2, wn * 32 + ni * 16 + l15, 256, k);
#pragma unroll
            for (int mi = 0; mi < 2; ++mi)
#pragma unroll
                for (int ni = 0; ni < 2; ++ni)
                    acc2[mi][ni] = __builtin_amdgcn_mfma_f32_16x16x32_f16(
                        b[ni], a[mi], acc2[mi][ni], 0, 0, 0);
        }

        // ---- T14 late prefetch: acc/acc2 mostly dead, pressure minimal ----
        {
            int nt = tile + gridDim.x;
            pA0 = (float4){0.f, 0.f, 0.f, 0.f};
            pA1 = (float4){0.f, 0.f, 0.f, 0.f};
            if (nt < ntiles) {
                int e = nt * TE + pr;
                if (e < E) {
                    const float4* g = (const float4*)(edge_attr + (size_t)e * RD + pc);
                    pA0 = g[0]; pA1 = g[1];
                }
            }
        }

        // ---- epilogue: cutoff-scale, pack half4, store direct to Wp ----
#pragma unroll
        for (int mi = 0; mi < 2; ++mi) {
            int el = wm * 32 + mi * 16 + l15;
            int ge = e0 + el;
            float d = dmt[mi];
            int pv = pvt[mi];
            float C = (d < RC_CUT)
                        ? 0.5f * (__cosf(d * 0.6283185307179586f) + 1.0f)
                        : 0.0f;
            if (ge < E) {
#pragma unroll
                for (int ni = 0; ni < 2; ++ni) {
                    float4 bv = *(const float4*)(fb2 + fbase[ni]);
                    half4_t hv;
                    hv[0] = (_Float16)((acc2[mi][ni][0] + bv.x) * C);
                    hv[1] = (_Float16)((acc2[mi][ni][1] + bv.y) * C);
                    hv[2] = (_Float16)((acc2[mi][ni][2] + bv.z) * C);
                    hv[3] = (_Float16)((acc2[mi][ni][3] + bv.w) * C);
                    *(half4_t*)(Wp + (size_t)pv * FD + fbase[ni]) = hv;
                }
            }
        }
        __syncthreads();   // T consumed; next tile may overwrite sT
    }
}

// ==================== PHASE B: quarter-wave aggregation (f16 h) ==============
// Wave per dst row, 4 quarter-waves x half8/lane. h is f16 (12.8 MB: fits
// the 32 MB aggregate L2), halving gather traffic vs f32. Plain cached
// loads everywhere. Writes raw aggregation into out (scratch); final_kernel
// (after the if/else) transforms it in place — it MUST run on this path
// too (R15/R16 failure mode).
__global__ __launch_bounds__(256) void agg_kernel(
    const _Float16* __restrict__ Wp,
    const unsigned int* __restrict__ meta,
    const int* __restrict__ offs,
    const _Float16* __restrict__ h,
    float* __restrict__ agg, int n)
{
    int g = blockIdx.x * 4 + (threadIdx.x >> 6);
    if (g >= n) return;
    int lane = threadIdx.x & 63;
    int q    = lane >> 4;          // quarter index = edge slot 0..3
    int col  = (lane & 15) * 8;    // 8 columns per lane
    int p  = offs[g];
    int p1 = offs[g + 1];

    float acc[8];
#pragma unroll
    for (int j = 0; j < 8; ++j) acc[j] = 0.0f;

    for (; p + 8 <= p1; p += 8) {
        unsigned mA = meta[p + q];
        unsigned mB = meta[p + 4 + q];
        half8_t wA = *(const half8_t*)(Wp + (size_t)(p + q) * FD + col);
        half8_t wB = *(const half8_t*)(Wp + (size_t)(p + 4 + q) * FD + col);
        half8_t hA = *(const half8_t*)(h + (size_t)(mA & 0xFFFFu) * FD + col);
        half8_t hB = *(const half8_t*)(h + (size_t)(mB & 0xFFFFu) * FD + col);
#pragma unroll
        for (int j = 0; j < 8; ++j)
            acc[j] += (float)wA[j] * (float)hA[j] + (float)wB[j] * (float)hB[j];
    }
    for (; p + 4 <= p1; p += 4) {
        unsigned mA = meta[p + q];
        half8_t wA = *(const half8_t*)(Wp + (size_t)(p + q) * FD + col);
        half8_t hA = *(const half8_t*)(h + (size_t)(mA & 0xFFFFu) * FD + col);
#pragma unroll
        for (int j = 0; j < 8; ++j) acc[j] += (float)wA[j] * (float)hA[j];
    }
    if (p + q < p1) {              // tail: 0..3 edges, one per quarter
        unsigned mA = meta[p + q];
        half8_t wA = *(const half8_t*)(Wp + (size_t)(p + q) * FD + col);
        half8_t hA = *(const half8_t*)(h + (size_t)(mA & 0xFFFFu) * FD + col);
#pragma unroll
        for (int j = 0; j < 8; ++j) acc[j] += (float)wA[j] * (float)hA[j];
    }

    // combine the 4 quarter-waves (lanes l, l+16, l+32, l+48 share cols)
#pragma unroll
    for (int j = 0; j < 8; ++j) {
        acc[j] += __shfl_xor(acc[j], 16);
        acc[j] += __shfl_xor(acc[j], 32);
    }
    if (q == 0) {
        float* ar = agg + (size_t)g * FD + col;
        *(float4*)ar       = (float4){acc[0], acc[1], acc[2], acc[3]};
        *(float4*)(ar + 4) = (float4){acc[4], acc[5], acc[6], acc[7]};
    }
}

// ==================== FALLBACK: fused kernel (global atomics, h f16) =========
__global__ __launch_bounds__(1024, 8) void edge_kernel_atomic(
    const float* __restrict__ edge_weight,
    const float* __restrict__ edge_attr,
    const float* __restrict__ fw1, const float* __restrict__ fb1,
    const float* __restrict__ fw2, const float* __restrict__ fb2,
    const int* __restrict__ eidx,
    const _Float16* __restrict__ h,
    float* agg, int E, int ntiles)
{
    extern __shared__ char smem[];
    char* sT  = smem;
    char* sB1 = smem + 32768;
    char* sB2 = smem + 49152;

    for (int i = threadIdx.x * 8; i < FD * RD; i += blockDim.x * 8) {
        int r = i >> 6, c = i & 63;
        const float4* g = (const float4*)(fw1 + (size_t)r * RD + c);
        float4 v0 = g[0], v1 = g[1];
        half8_t hv;
        hv[0] = (_Float16)v0.x; hv[1] = (_Float16)v0.y;
        hv[2] = (_Float16)v0.z; hv[3] = (_Float16)v0.w;
        hv[4] = (_Float16)v1.x; hv[5] = (_Float16)v1.y;
        hv[6] = (_Float16)v1.z; hv[7] = (_Float16)v1.w;
        *(half8_t*)(sB1 + r * 128 + ((c * 2) ^ ((r & 7) << 4))) = hv;
    }
    for (int i = threadIdx.x * 8; i < FD * FD; i += blockDim.x * 8) {
        int r = i >> 7, c = i & 127;
        const float4* g = (const float4*)(fw2 + (size_t)r * FD + c);
        float4 v0 = g[0], v1 = g[1];
        half8_t hv;
        hv[0] = (_Float16)v0.x; hv[1] = (_Float16)v0.y;
        hv[2] = (_Float16)v0.z; hv[3] = (_Float16)v0.w;
        hv[4] = (_Float16)v1.x; hv[5] = (_Float16)v1.y;
        hv[6] = (_Float16)v1.z; hv[7] = (_Float16)v1.w;
        *(half8_t*)(sB2 + r * 256 + ((c * 2) ^ ((r & 7) << 4))) = hv;
    }
    __syncthreads();

    const int* srcp = eidx;
    const int* dstp = eidx + E;
    int lane = threadIdx.x & 63;
    int wid  = threadIdx.x >> 6;
    int wm = wid >> 2;
    int wn = wid & 3;
    int l15 = lane & 15;
    int l4  = lane >> 4;

    for (int tile = blockIdx.x; tile < ntiles; tile += gridDim.x) {
        int e0 = tile * TE;
        for (int i = threadIdx.x * 8; i < TE * RD; i += blockDim.x * 8) {
            int r = i >> 6, c = i & 63;
            half8_t hv;
            if (e0 + r < E) {
                const float4* g = (const float4*)(edge_attr + (size_t)(e0 + r) * RD + c);
                float4 v0 = g[0], v1 = g[1];
                hv[0] = (_Float16)v0.x; hv[1] = (_Float16)v0.y;
                hv[2] = (_Float16)v0.z; hv[3] = (_Float16)v0.w;
                hv[4] = (_Float16)v1.x; hv[5] = (_Float16)v1.y;
                hv[6] = (_Float16)v1.z; hv[7] = (_Float16)v1.w;
            } else {
                for (int q = 0; q < 8; ++q) hv[q] = (_Float16)0.0f;
            }
            *(half8_t*)(sT + r * 128 + ((c * 2) ^ ((r & 7) << 4))) = hv;
        }
        __syncthreads();

        floatx4 acc[2][2];
#pragma unroll
        for (int mi = 0; mi < 2; ++mi)
#pragma unroll
            for (int ni = 0; ni < 2; ++ni)
                acc[mi][ni] = (floatx4){0.f, 0.f, 0.f, 0.f};
#pragma unroll
        for (int ks = 0; ks < 2; ++ks) {
            int k = ks * 32 + l4 * 8;
            half8_t a[2], b[2];
#pragma unroll
            for (int mi = 0; mi < 2; ++mi)
                a[mi] = lds_read8(sT, wm * 32 + mi * 16 + l15, 128, k);
#pragma unroll
            for (int ni = 0; ni < 2; ++ni)
                b[ni] = lds_read8(sB1, wn * 32 + ni * 16 + l15, 128, k);
#pragma unroll
            for (int mi = 0; mi < 2; ++mi)
#pragma unroll
                for (int ni = 0; ni < 2; ++ni)
                    acc[mi][ni] = __builtin_amdgcn_mfma_f32_16x16x32_f16(
                        a[mi], b[ni], acc[mi][ni], 0, 0, 0);
        }
        __syncthreads();

#pragma unroll
        for (int ni = 0; ni < 2; ++ni) {
            int f = wn * 32 + ni * 16 + l15;
            float bias = fb1[f];
#pragma unroll
            for (int mi = 0; mi < 2; ++mi) {
#pragma unroll
                for (int j = 0; j < 4; ++j) {
                    int e = wm * 32 + mi * 16 + l4 * 4 + j;
                    float t = fast_tanh(acc[mi][ni][j] + bias);
                    *(_Float16*)(sT + e * 256 + ((f * 2) ^ ((e & 7) << 4))) =
                        (_Float16)t;
                }
            }
        }
        __syncthreads();

        floatx4 acc2[2][2];
#pragma unroll
        for (int mi = 0; mi < 2; ++mi)
#pragma unroll
            for (int ni = 0; ni < 2; ++ni)
                acc2[mi][ni] = (floatx4){0.f, 0.f, 0.f, 0.f};
#pragma unroll
        for (int ks = 0; ks < 4; ++ks) {
            int k = ks * 32 + l4 * 8;
            half8_t a[2], b[2];
#pragma unroll
            for (int mi = 0; mi < 2; ++mi)
                a[mi] = lds_read8(sT, wm * 32 + mi * 16 + l15, 256, k);
#pragma unroll
            for (int ni = 0; ni < 2; ++ni)
                b[ni] = lds_read8(sB2, wn * 32 + ni * 16 + l15, 256, k);
#pragma unroll
            for (int mi = 0; mi < 2; ++mi)
#pragma unroll
                for (int ni = 0; ni < 2; ++ni)
                    acc2[mi][ni] = __builtin_amdgcn_mfma_f32_16x16x32_f16(
                        a[mi], b[ni], acc2[mi][ni], 0, 0, 0);
        }
        __syncthreads();

        float bias2[2];
        int gcol[2];
#pragma unroll
        for (int ni = 0; ni < 2; ++ni) {
            gcol[ni] = wn * 32 + ni * 16 + l15;
            bias2[ni] = fb2[gcol[ni]];
        }
#pragma unroll
        for (int mi = 0; mi < 2; ++mi) {
            int ge[4], s4[4], dn4[4];
            float d4[4];
#pragma unroll
            for (int j = 0; j < 4; ++j) {
                int el = wm * 32 + mi * 16 + l4 * 4 + j;
                ge[j] = e0 + el;
                int idx = (ge[j] < E) ? ge[j] : (E - 1);
                s4[j]  = srcp[idx];
                dn4[j] = dstp[idx];
                d4[j]  = edge_weight[idx];
            }
#pragma unroll
            for (int j = 0; j < 4; ++j) {
                if (ge[j] >= E) continue;
                float C = (d4[j] < RC_CUT)
                            ? 0.5f * (__cosf(d4[j] * 0.6283185307179586f) + 1.0f)
                            : 0.0f;
                const _Float16* hrow = h + (size_t)s4[j] * FD;
                float* ar = agg + (size_t)dn4[j] * FD;
#pragma unroll
                for (int ni = 0; ni < 2; ++ni) {
                    int g = gcol[ni];
                    float wv = (acc2[mi][ni][j] + bias2[ni]) * C;
                    atomicAdd(ar + g, wv * (float)hrow[g]);
                }
            }
        }
    }
}

// ---------------- final: disc conv + lin2 + tanh + lin (h f16) --------------
// Runs on BOTH paths, transforming the aggregation in out -> final output.
__global__ __launch_bounds__(256) void final_kernel(
    const float* aggin, const _Float16* __restrict__ h,
    const float* __restrict__ disc_w,
    const float* __restrict__ lin2_w, const float* __restrict__ lin2_b,
    const float* __restrict__ lin_w, const float* __restrict__ lin_b,
    float* out, int n)
{
    __shared__ float sg[16][FD];
    __shared__ float sm[16][FD];
    int base = blockIdx.x * 16;
    for (int i = threadIdx.x; i < 16 * FD; i += 256) {
        int r = i >> 7, c = i & 127;
        int row = base + r;
        float v = 0.0f;
        if (row < n) {
            v = aggin[(size_t)row * FD + c]
              + disc_w[c] * (float)h[(size_t)row * FD + c];
            if (row + 1 < n)
                v += disc_w[FD + c] * (float)h[(size_t)(row + 1) * FD + c];
            if (row >= 1)
                v += disc_w[2 * FD + c] * (float)h[(size_t)(row - 1) * FD + c];
        }
        sg[r][c] = v;
    }
    __syncthreads();
    int f = threadIdx.x & 127;
    int half = threadIdx.x >> 7;
    {
        float acc[8];
        float b = lin2_b[f];
#pragma unroll
        for (int r = 0; r < 8; ++r) acc[r] = b;
        const float* wrow = lin2_w + (size_t)f * FD;
        for (int k = 0; k < FD; k += 4) {
            float4 wv = *(const float4*)(wrow + k);
#pragma unroll
            for (int r = 0; r < 8; ++r) {
                acc[r] += sg[half * 8 + r][k]     * wv.x;
                acc[r] += sg[half * 8 + r][k + 1] * wv.y;
                acc[r] += sg[half * 8 + r][k + 2] * wv.z;
                acc[r] += sg[half * 8 + r][k + 3] * wv.w;
            }
        }
#pragma unroll
        for (int r = 0; r < 8; ++r) sm[half * 8 + r][f] = fast_tanh(acc[r]);
    }
    __syncthreads();
    {
        float acc[8];
        float b = lin_b[f];
#pragma unroll
        for (int r = 0; r < 8; ++r) acc[r] = b;
        const float* wrow = lin_w + (size_t)f * HD;
        for (int k = 0; k < FD; k += 4) {
            float4 wv = *(const float4*)(wrow + k);
#pragma unroll
            for (int r = 0; r < 8; ++r) {
                acc[r] += sm[half * 8 + r][k]     * wv.x;
                acc[r] += sm[half * 8 + r][k + 1] * wv.y;
                acc[r] += sm[half * 8 + r][k + 2] * wv.z;
                acc[r] += sm[half * 8 + r][k + 3] * wv.w;
            }
        }
#pragma unroll
        for (int r = 0; r < 8; ++r) {
            int row = base + half * 8 + r;
            if (row < n) out[(size_t)row * HD + f] = acc[r];
        }
    }
}

extern "C" void kernel_launch(void* const* d_in, const int* in_sizes, int n_in,
                              void* d_out, int out_size, void* d_ws, size_t ws_size,
                              hipStream_t stream)
{
    const float* x      = (const float*)d_in[0];
    const float* ew     = (const float*)d_in[1];
    const float* ea     = (const float*)d_in[2];
    const float* fw1    = (const float*)d_in[3];
    const float* fb1    = (const float*)d_in[4];
    const float* fw2    = (const float*)d_in[5];
    const float* fb2    = (const float*)d_in[6];
    const float* lin1_w = (const float*)d_in[7];
    const float* lin2_w = (const float*)d_in[8];
    const float* lin2_b = (const float*)d_in[9];
    const float* disc_w = (const float*)d_in[10];
    const float* lin_w  = (const float*)d_in[11];
    const float* lin_b  = (const float*)d_in[12];
    const int*   eidx   = (const int*)d_in[13];

    int n = in_sizes[0] / HD;
    int E = in_sizes[1];
    int ntiles = (E + TE - 1) / TE;
    int nb = (n + 255) / 256;
    float* out = (float*)d_out;

    const int* srcp = eidx;
    const int* dstp = eidx + E;

    // workspace layout (16B-aligned sections)
    char* base = (char*)d_ws;
    _Float16*  h    = (_Float16*)base;                    // n*128 f16
    size_t off_h    = (size_t)n * FD * 2;
    _Float16*  Wp   = (_Float16*)(base + off_h);          // E*128 f16
    size_t off_w    = off_h + (size_t)E * FD * 2;
    int*       inv  = (int*)(base + off_w);               // E ints
    size_t off_i    = off_w + (size_t)E * 4;
    unsigned int* meta = (unsigned int*)(base + off_i);   // E u32
    size_t off_m    = off_i + (size_t)E * 4;
    int*       cnt  = (int*)(base + off_m);               // n ints (per-dst)
    int*       offs = cnt + n;                            // n+1 ints
    int*       bsum = offs + n + 1;                       // nb ints
    size_t need     = off_m + (size_t)(2 * n + nb + 16) * 4;

    lin1_kernel<<<(n + 15) / 16, 256, 0, stream>>>(x, lin1_w, h, n);

    size_t smem = 81920;   // 80 KB -> 2 blocks/CU
    if (ws_size >= need && n <= 65535) {
        // ---------- two-phase path: sorted-by-dst, quarter-wave agg ----------
        hipMemsetAsync(cnt, 0, (size_t)n * sizeof(int), stream);
        count_kernel<<<2048, 256, 0, stream>>>(dstp, cnt, E);
        scan1_kernel<<<nb, 256, 0, stream>>>(cnt, bsum, n);
        scan2_kernel<<<1, 64, 0, stream>>>(bsum, nb, offs + n);
        scan3_kernel<<<nb, 256, 0, stream>>>(cnt, bsum, offs, n);
        scatter_kernel<<<2048, 256, 0, stream>>>(srcp, dstp, cnt, inv, meta, E);

        hipFuncSetAttribute((const void*)edge_gemm_kernel,
                            hipFuncAttributeMaxDynamicSharedMemorySize, (int)smem);
        int nblocks = ntiles < 512 ? ntiles : 512;
        edge_gemm_kernel<<<nblocks, 1024, smem, stream>>>(ew, ea, fw1, fb1, fw2, fb2,
                                                          inv, Wp, E, ntiles);

        agg_kernel<<<(n + 3) / 4, 256, 0, stream>>>(Wp, meta, offs, h, out, n);
    } else {
        // ---------- fallback: proven fused atomic kernel ----------
        hipMemsetAsync(d_out, 0, (size_t)out_size * sizeof(float), stream);
        hipFuncSetAttribute((const void*)edge_kernel_atomic,
                            hipFuncAttributeMaxDynamicSharedMemorySize, (int)smem);
        int nblocks = ntiles < 512 ? ntiles : 512;
        edge_kernel_atomic<<<nblocks, 1024, smem, stream>>>(ew, ea, fw1, fb1, fw2, fb2,
                                                            eidx, h, out, E, ntiles);
    }

    final_kernel<<<(n + 15) / 16, 256, 0, stream>>>(out, h, disc_w, lin2_w, lin2_b,
                                                    lin_w, lin_b, out, n);
}

// Round 19
// 800.609 us; speedup vs baseline: 1.0079x; 1.0079x over previous
//
#include <hip/hip_runtime.h>
#include <math.h>

#define HD 128
#define FD 128
#define RD 64
#define TE 128          // edges per tile
#define RC_CUT 5.0f

typedef _Float16 half8_t __attribute__((ext_vector_type(8)));
typedef _Float16 half4_t __attribute__((ext_vector_type(4)));
typedef float floatx4 __attribute__((ext_vector_type(4)));

__device__ __forceinline__ float fast_tanh(float x) {
    float ex = __expf(2.0f * x);
    return 1.0f - 2.0f / (ex + 1.0f);
}

// ---------------- lin1: h = x @ lin1_w.T  (h stored f16) ----------------
__global__ __launch_bounds__(256) void lin1_kernel(const float* __restrict__ x,
                                                   const float* __restrict__ w,
                                                   _Float16* __restrict__ h, int n)
{
    __shared__ float sx[16][HD];
    int base = blockIdx.x * 16;
    for (int i = threadIdx.x; i < 16 * HD; i += 256) {
        int r = i >> 7, c = i & 127;
        int row = base + r;
        sx[r][c] = (row < n) ? x[(size_t)row * HD + c] : 0.0f;
    }
    __syncthreads();
    int f = threadIdx.x & 127;
    int half = threadIdx.x >> 7;
    float acc[8];
#pragma unroll
    for (int r = 0; r < 8; ++r) acc[r] = 0.0f;
    const float* wrow = w + (size_t)f * HD;
    for (int k = 0; k < HD; k += 4) {
        float4 wv = *(const float4*)(wrow + k);
#pragma unroll
        for (int r = 0; r < 8; ++r) {
            acc[r] += sx[half * 8 + r][k]     * wv.x;
            acc[r] += sx[half * 8 + r][k + 1] * wv.y;
            acc[r] += sx[half * 8 + r][k + 2] * wv.z;
            acc[r] += sx[half * 8 + r][k + 3] * wv.w;
        }
    }
#pragma unroll
    for (int r = 0; r < 8; ++r) {
        int row = base + half * 8 + r;
        if (row < n) h[(size_t)row * FD + f] = (_Float16)acc[r];
    }
}

// ---------------- bucketing by dst: count / 3-level scan / scatter ----------
__global__ __launch_bounds__(256) void count_kernel(const int* __restrict__ dstp,
                                                    int* cnt, int E)
{
    for (int e = blockIdx.x * blockDim.x + threadIdx.x; e < E;
         e += gridDim.x * blockDim.x)
        atomicAdd(&cnt[dstp[e]], 1);
}

__global__ __launch_bounds__(256) void scan1_kernel(const int* __restrict__ cnt,
                                                    int* bsum, int n)
{
    int i = blockIdx.x * 256 + threadIdx.x;
    int v = (i < n) ? cnt[i] : 0;
    int lane = threadIdx.x & 63;
    int wv = threadIdx.x >> 6;
    int s = v;
#pragma unroll
    for (int d = 1; d < 64; d <<= 1) s += __shfl_xor(s, d);
    __shared__ int ws[4];
    if (lane == 0) ws[wv] = s;
    __syncthreads();
    if (threadIdx.x == 0) bsum[blockIdx.x] = ws[0] + ws[1] + ws[2] + ws[3];
}

__global__ void scan2_kernel(int* bsum, int nb, int* totalp)
{
    int lane = threadIdx.x;
    int carry = 0;
    for (int base = 0; base < nb; base += 64) {
        int i = base + lane;
        int v = (i < nb) ? bsum[i] : 0;
        int orig = v;
#pragma unroll
        for (int d = 1; d < 64; d <<= 1) {
            int t = __shfl_up(v, d);
            if (lane >= d) v += t;
        }
        if (i < nb) bsum[i] = carry + v - orig;
        carry += __shfl(v, 63);
    }
    if (lane == 0) *totalp = carry;
}

__global__ __launch_bounds__(256) void scan3_kernel(int* cnt, const int* __restrict__ bsum,
                                                    int* offs, int n)
{
    int i = blockIdx.x * 256 + threadIdx.x;
    int v = (i < n) ? cnt[i] : 0;
    int lane = threadIdx.x & 63;
    int wv = threadIdx.x >> 6;
    int incl = v;
#pragma unroll
    for (int d = 1; d < 64; d <<= 1) {
        int t = __shfl_up(incl, d);
        if (lane >= d) incl += t;
    }
    __shared__ int ws[4];
    if (lane == 63) ws[wv] = incl;
    __syncthreads();
    int wbase = 0;
#pragma unroll
    for (int w = 0; w < 4; ++w) wbase += (w < wv) ? ws[w] : 0;
    int excl = bsum[blockIdx.x] + wbase + incl - v;
    if (i < n) { offs[i] = excl; cnt[i] = excl; }   // cnt becomes scatter cursor
}

// inv[e] = permuted position; meta[pos] = src | (dst << 16)  (n < 65536)
__global__ __launch_bounds__(256) void scatter_kernel(
    const int* __restrict__ srcp, const int* __restrict__ dstp,
    int* cursor, int* __restrict__ inv, unsigned int* __restrict__ meta, int E)
{
    for (int e = blockIdx.x * blockDim.x + threadIdx.x; e < E;
         e += gridDim.x * blockDim.x) {
        int d = dstp[e];
        int p = atomicAdd(&cursor[d], 1);
        inv[e] = p;
        meta[p] = (unsigned int)srcp[e] | ((unsigned int)d << 16);
    }
}

// ---------------- shared LDS helpers ----------------
__device__ __forceinline__ half8_t lds_read8(const char* base, int row,
                                             int rowstride, int col) {
    int off = row * rowstride + ((col * 2) ^ ((row & 7) << 4));
    return *(const half8_t*)(base + off);
}

// ==================== PHASE A: filter GEMMs, natural edge order ==============
// Exact R8/R9 structure (proven 353 us): swapped MFMA, half4 direct store of
// W = C*(filter) to Wp[inv[e]]; NO h access here (R10: mixing the h gather
// with the Wp write-combine stream doubles write traffic). Epilogue metadata
// loads stay IN the epilogue (R18: hoisting them to tile top cost +82 MB
// FETCH from lost L2 temporal locality, no latency win).
__global__ __launch_bounds__(1024, 8) void edge_gemm_kernel(
    const float* __restrict__ edge_weight,
    const float* __restrict__ edge_attr,
    const float* __restrict__ fw1, const float* __restrict__ fb1,
    const float* __restrict__ fw2, const float* __restrict__ fb2,
    const int* __restrict__ inv,
    _Float16* __restrict__ Wp,
    int E, int ntiles)
{
    extern __shared__ char smem[];
    char* sT  = smem;
    char* sB1 = smem + 32768;
    char* sB2 = smem + 49152;

    // ---- stage weights once per block (fp32 -> f16, swizzled) ----
    for (int i = threadIdx.x * 8; i < FD * RD; i += blockDim.x * 8) {
        int r = i >> 6, c = i & 63;
        const float4* g = (const float4*)(fw1 + (size_t)r * RD + c);
        float4 v0 = g[0], v1 = g[1];
        half8_t hv;
        hv[0] = (_Float16)v0.x; hv[1] = (_Float16)v0.y;
        hv[2] = (_Float16)v0.z; hv[3] = (_Float16)v0.w;
        hv[4] = (_Float16)v1.x; hv[5] = (_Float16)v1.y;
        hv[6] = (_Float16)v1.z; hv[7] = (_Float16)v1.w;
        *(half8_t*)(sB1 + r * 128 + ((c * 2) ^ ((r & 7) << 4))) = hv;
    }
    for (int i = threadIdx.x * 8; i < FD * FD; i += blockDim.x * 8) {
        int r = i >> 7, c = i & 127;
        const float4* g = (const float4*)(fw2 + (size_t)r * FD + c);
        float4 v0 = g[0], v1 = g[1];
        half8_t hv;
        hv[0] = (_Float16)v0.x; hv[1] = (_Float16)v0.y;
        hv[2] = (_Float16)v0.z; hv[3] = (_Float16)v0.w;
        hv[4] = (_Float16)v1.x; hv[5] = (_Float16)v1.y;
        hv[6] = (_Float16)v1.z; hv[7] = (_Float16)v1.w;
        *(half8_t*)(sB2 + r * 256 + ((c * 2) ^ ((r & 7) << 4))) = hv;
    }

    int lane = threadIdx.x & 63;
    int wid  = threadIdx.x >> 6;   // 0..15
    int wm = wid >> 2;             // 0..3  (edge dim, 32 each)
    int wn = wid & 3;              // 0..3  (filter dim, 32 each)
    int l15 = lane & 15;
    int l4  = lane >> 4;

    // swapped-fragment f-base per (ni): 4 consecutive f columns
    int fbase[2];
#pragma unroll
    for (int ni = 0; ni < 2; ++ni) fbase[ni] = wn * 32 + ni * 16 + l4 * 4;

    // prefetch lane mapping: thread -> (row, col8) of the 128x64 A tile
    int pr = threadIdx.x >> 3;          // 0..127
    int pc = (threadIdx.x & 7) * 8;     // 0..56

    // ---- prologue: prefetch first tile's A into registers ----
    float4 pA0 = {0.f, 0.f, 0.f, 0.f}, pA1 = {0.f, 0.f, 0.f, 0.f};
    {
        int e = blockIdx.x * TE + pr;
        if (e < E) {
            const float4* g = (const float4*)(edge_attr + (size_t)e * RD + pc);
            pA0 = g[0]; pA1 = g[1];
        }
    }
    __syncthreads();   // weights staged

    for (int tile = blockIdx.x; tile < ntiles; tile += gridDim.x) {
        int e0 = tile * TE;
        // ---- stage A from prefetch registers (cvt + ds_write only) ----
        {
            half8_t hv;
            hv[0] = (_Float16)pA0.x; hv[1] = (_Float16)pA0.y;
            hv[2] = (_Float16)pA0.z; hv[3] = (_Float16)pA0.w;
            hv[4] = (_Float16)pA1.x; hv[5] = (_Float16)pA1.y;
            hv[6] = (_Float16)pA1.z; hv[7] = (_Float16)pA1.w;
            *(half8_t*)(sT + pr * 128 + ((pc * 2) ^ ((pr & 7) << 4))) = hv;
        }
        __syncthreads();

        // ---- GEMM1 (swapped): accT[f-frag][e-col] ----
        floatx4 acc[2][2];
#pragma unroll
        for (int mi = 0; mi < 2; ++mi)
#pragma unroll
            for (int ni = 0; ni < 2; ++ni)
                acc[mi][ni] = (floatx4){0.f, 0.f, 0.f, 0.f};
#pragma unroll
        for (int ks = 0; ks < 2; ++ks) {
            int k = ks * 32 + l4 * 8;
            half8_t a[2], b[2];
#pragma unroll
            for (int mi = 0; mi < 2; ++mi)
                a[mi] = lds_read8(sT, wm * 32 + mi * 16 + l15, 128, k);
#pragma unroll
            for (int ni = 0; ni < 2; ++ni)
                b[ni] = lds_read8(sB1, wn * 32 + ni * 16 + l15, 128, k);
#pragma unroll
            for (int mi = 0; mi < 2; ++mi)
#pragma unroll
                for (int ni = 0; ni < 2; ++ni)
                    acc[mi][ni] = __builtin_amdgcn_mfma_f32_16x16x32_f16(
                        b[ni], a[mi], acc[mi][ni], 0, 0, 0);
        }
        __syncthreads();

        // ---- bias + tanh -> T (one ds_write_b64 per fragment) ----
#pragma unroll
        for (int ni = 0; ni < 2; ++ni) {
            float4 bv = *(const float4*)(fb1 + fbase[ni]);
#pragma unroll
            for (int mi = 0; mi < 2; ++mi) {
                int e = wm * 32 + mi * 16 + l15;
                half4_t hv;
                hv[0] = (_Float16)fast_tanh(acc[mi][ni][0] + bv.x);
                hv[1] = (_Float16)fast_tanh(acc[mi][ni][1] + bv.y);
                hv[2] = (_Float16)fast_tanh(acc[mi][ni][2] + bv.z);
                hv[3] = (_Float16)fast_tanh(acc[mi][ni][3] + bv.w);
                *(half4_t*)(sT + e * 256 + ((fbase[ni] * 2) ^ ((e & 7) << 4))) = hv;
            }
        }
        __syncthreads();

        // ---- GEMM2 (swapped): accT2[f-frag][e-col] ----
        floatx4 acc2[2][2];
#pragma unroll
        for (int mi = 0; mi < 2; ++mi)
#pragma unroll
            for (int ni = 0; ni < 2; ++ni)
                acc2[mi][ni] = (floatx4){0.f, 0.f, 0.f, 0.f};
#pragma unroll
        for (int ks = 0; ks < 4; ++ks) {
            int k = ks * 32 + l4 * 8;
            half8_t a[2], b[2];
#pragma unroll
            for (int mi = 0; mi < 2; ++mi)
                a[mi] = lds_read8(sT, wm * 32 + mi * 16 + l15, 256, k);
#pragma unroll
            for (int ni = 0; ni < 2; ++ni)
                b[ni] = lds_read8(sB2, wn * 32 + ni * 16 + l15, 256, k);
#pragma unroll
            for (int mi = 0; mi < 2; ++mi)
#pragma unroll
                for (int ni = 0; ni < 2; ++ni)
                    acc2[mi][ni] = __builtin_amdgcn_mfma_f32_16x16x32_f16(
                        b[ni], a[mi], acc2[mi][ni], 0, 0, 0);
        }

        // ---- T14 late prefetch: acc/acc2 mostly dead, pressure minimal ----
        {
            int nt = tile + gridDim.x;
            pA0 = (float4){0.f, 0.f, 0.f, 0.f};
            pA1 = (float4){0.f, 0.f, 0.f, 0.f};
            if (nt < ntiles) {
                int e = nt * TE + pr;
                if (e < E) {
                    const float4* g = (const float4*)(edge_attr + (size_t)e * RD + pc);
                    pA0 = g[0]; pA1 = g[1];
                }
            }
        }

        // ---- epilogue: cutoff-scale, pack half4, store direct to Wp ----
#pragma unroll
        for (int mi = 0; mi < 2; ++mi) {
            int el = wm * 32 + mi * 16 + l15;
            int ge = e0 + el;
            int idx = (ge < E) ? ge : (E - 1);
            float d = edge_weight[idx];
            int pv = inv[idx];
            float C = (d < RC_CUT)
                        ? 0.5f * (__cosf(d * 0.6283185307179586f) + 1.0f)
                        : 0.0f;
            if (ge < E) {
#pragma unroll
                for (int ni = 0; ni < 2; ++ni) {
                    float4 bv = *(const float4*)(fb2 + fbase[ni]);
                    half4_t hv;
                    hv[0] = (_Float16)((acc2[mi][ni][0] + bv.x) * C);
                    hv[1] = (_Float16)((acc2[mi][ni][1] + bv.y) * C);
                    hv[2] = (_Float16)((acc2[mi][ni][2] + bv.z) * C);
                    hv[3] = (_Float16)((acc2[mi][ni][3] + bv.w) * C);
                    *(half4_t*)(Wp + (size_t)pv * FD + fbase[ni]) = hv;
                }
            }
        }
        __syncthreads();   // T consumed; next tile may overwrite sT
    }
}

// ==================== PHASE B: quarter-wave aggregation (f16 h) ==============
// Wave per dst row, 4 quarter-waves x half8/lane. h is f16 (12.8 MB: fits
// the 32 MB aggregate L2), halving gather traffic vs f32. Plain cached
// loads everywhere. Writes raw aggregation into out (scratch); final_kernel
// (after the if/else) transforms it in place — it MUST run on this path
// too (R15/R16 failure mode).
__global__ __launch_bounds__(256) void agg_kernel(
    const _Float16* __restrict__ Wp,
    const unsigned int* __restrict__ meta,
    const int* __restrict__ offs,
    const _Float16* __restrict__ h,
    float* __restrict__ agg, int n)
{
    int g = blockIdx.x * 4 + (threadIdx.x >> 6);
    if (g >= n) return;
    int lane = threadIdx.x & 63;
    int q    = lane >> 4;          // quarter index = edge slot 0..3
    int col  = (lane & 15) * 8;    // 8 columns per lane
    int p  = offs[g];
    int p1 = offs[g + 1];

    float acc[8];
#pragma unroll
    for (int j = 0; j < 8; ++j) acc[j] = 0.0f;

    for (; p + 8 <= p1; p += 8) {
        unsigned mA = meta[p + q];
        unsigned mB = meta[p + 4 + q];
        half8_t wA = *(const half8_t*)(Wp + (size_t)(p + q) * FD + col);
        half8_t wB = *(const half8_t*)(Wp + (size_t)(p + 4 + q) * FD + col);
        half8_t hA = *(const half8_t*)(h + (size_t)(mA & 0xFFFFu) * FD + col);
        half8_t hB = *(const half8_t*)(h + (size_t)(mB & 0xFFFFu) * FD + col);
#pragma unroll
        for (int j = 0; j < 8; ++j)
            acc[j] += (float)wA[j] * (float)hA[j] + (float)wB[j] * (float)hB[j];
    }
    for (; p + 4 <= p1; p += 4) {
        unsigned mA = meta[p + q];
        half8_t wA = *(const half8_t*)(Wp + (size_t)(p + q) * FD + col);
        half8_t hA = *(const half8_t*)(h + (size_t)(mA & 0xFFFFu) * FD + col);
#pragma unroll
        for (int j = 0; j < 8; ++j) acc[j] += (float)wA[j] * (float)hA[j];
    }
    if (p + q < p1) {              // tail: 0..3 edges, one per quarter
        unsigned mA = meta[p + q];
        half8_t wA = *(const half8_t*)(Wp + (size_t)(p + q) * FD + col);
        half8_t hA = *(const half8_t*)(h + (size_t)(mA & 0xFFFFu) * FD + col);
#pragma unroll
        for (int j = 0; j < 8; ++j) acc[j] += (float)wA[j] * (float)hA[j];
    }

    // combine the 4 quarter-waves (lanes l, l+16, l+32, l+48 share cols)
#pragma unroll
    for (int j = 0; j < 8; ++j) {
        acc[j] += __shfl_xor(acc[j], 16);
        acc[j] += __shfl_xor(acc[j], 32);
    }
    if (q == 0) {
        float* ar = agg + (size_t)g * FD + col;
        *(float4*)ar       = (float4){acc[0], acc[1], acc[2], acc[3]};
        *(float4*)(ar + 4) = (float4){acc[4], acc[5], acc[6], acc[7]};
    }
}

// ==================== FALLBACK: fused kernel (global atomics, h f16) =========
__global__ __launch_bounds__(1024, 8) void edge_kernel_atomic(
    const float* __restrict__ edge_weight,
    const float* __restrict__ edge_attr,
    const float* __restrict__ fw1, const float* __restrict__ fb1,
    const float* __restrict__ fw2, const float* __restrict__ fb2,
    const int* __restrict__ eidx,
    const _Float16* __restrict__ h,
    float* agg, int E, int ntiles)
{
    extern __shared__ char smem[];
    char* sT  = smem;
    char* sB1 = smem + 32768;
    char* sB2 = smem + 49152;

    for (int i = threadIdx.x * 8; i < FD * RD; i += blockDim.x * 8) {
        int r = i >> 6, c = i & 63;
        const float4* g = (const float4*)(fw1 + (size_t)r * RD + c);
        float4 v0 = g[0], v1 = g[1];
        half8_t hv;
        hv[0] = (_Float16)v0.x; hv[1] = (_Float16)v0.y;
        hv[2] = (_Float16)v0.z; hv[3] = (_Float16)v0.w;
        hv[4] = (_Float16)v1.x; hv[5] = (_Float16)v1.y;
        hv[6] = (_Float16)v1.z; hv[7] = (_Float16)v1.w;
        *(half8_t*)(sB1 + r * 128 + ((c * 2) ^ ((r & 7) << 4))) = hv;
    }
    for (int i = threadIdx.x * 8; i < FD * FD; i += blockDim.x * 8) {
        int r = i >> 7, c = i & 127;
        const float4* g = (const float4*)(fw2 + (size_t)r * FD + c);
        float4 v0 = g[0], v1 = g[1];
        half8_t hv;
        hv[0] = (_Float16)v0.x; hv[1] = (_Float16)v0.y;
        hv[2] = (_Float16)v0.z; hv[3] = (_Float16)v0.w;
        hv[4] = (_Float16)v1.x; hv[5] = (_Float16)v1.y;
        hv[6] = (_Float16)v1.z; hv[7] = (_Float16)v1.w;
        *(half8_t*)(sB2 + r * 256 + ((c * 2) ^ ((r & 7) << 4))) = hv;
    }
    __syncthreads();

    const int* srcp = eidx;
    const int* dstp = eidx + E;
    int lane = threadIdx.x & 63;
    int wid  = threadIdx.x >> 6;
    int wm = wid >> 2;
    int wn = wid & 3;
    int l15 = lane & 15;
    int l4  = lane >> 4;

    for (int tile = blockIdx.x; tile < ntiles; tile += gridDim.x) {
        int e0 = tile * TE;
        for (int i = threadIdx.x * 8; i < TE * RD; i += blockDim.x * 8) {
            int r = i >> 6, c = i & 63;
            half8_t hv;
            if (e0 + r < E) {
                const float4* g = (const float4*)(edge_attr + (size_t)(e0 + r) * RD + c);
                float4 v0 = g[0], v1 = g[1];
                hv[0] = (_Float16)v0.x; hv[1] = (_Float16)v0.y;
                hv[2] = (_Float16)v0.z; hv[3] = (_Float16)v0.w;
                hv[4] = (_Float16)v1.x; hv[5] = (_Float16)v1.y;
                hv[6] = (_Float16)v1.z; hv[7] = (_Float16)v1.w;
            } else {
                for (int q = 0; q < 8; ++q) hv[q] = (_Float16)0.0f;
            }
            *(half8_t*)(sT + r * 128 + ((c * 2) ^ ((r & 7) << 4))) = hv;
        }
        __syncthreads();

        floatx4 acc[2][2];
#pragma unroll
        for (int mi = 0; mi < 2; ++mi)
#pragma unroll
            for (int ni = 0; ni < 2; ++ni)
                acc[mi][ni] = (floatx4){0.f, 0.f, 0.f, 0.f};
#pragma unroll
        for (int ks = 0; ks < 2; ++ks) {
            int k = ks * 32 + l4 * 8;
            half8_t a[2], b[2];
#pragma unroll
            for (int mi = 0; mi < 2; ++mi)
                a[mi] = lds_read8(sT, wm * 32 + mi * 16 + l15, 128, k);
#pragma unroll
            for (int ni = 0; ni < 2; ++ni)
                b[ni] = lds_read8(sB1, wn * 32 + ni * 16 + l15, 128, k);
#pragma unroll
            for (int mi = 0; mi < 2; ++mi)
#pragma unroll
                for (int ni = 0; ni < 2; ++ni)
                    acc[mi][ni] = __builtin_amdgcn_mfma_f32_16x16x32_f16(
                        a[mi], b[ni], acc[mi][ni], 0, 0, 0);
        }
        __syncthreads();

#pragma unroll
        for (int ni = 0; ni < 2; ++ni) {
            int f = wn * 32 + ni * 16 + l15;
            float bias = fb1[f];
#pragma unroll
            for (int mi = 0; mi < 2; ++mi) {
#pragma unroll
                for (int j = 0; j < 4; ++j) {
                    int e = wm * 32 + mi * 16 + l4 * 4 + j;
                    float t = fast_tanh(acc[mi][ni][j] + bias);
                    *(_Float16*)(sT + e * 256 + ((f * 2) ^ ((e & 7) << 4))) =
                        (_Float16)t;
                }
            }
        }
        __syncthreads();

        floatx4 acc2[2][2];
#pragma unroll
        for (int mi = 0; mi < 2; ++mi)
#pragma unroll
            for (int ni = 0; ni < 2; ++ni)
                acc2[mi][ni] = (floatx4){0.f, 0.f, 0.f, 0.f};
#pragma unroll
        for (int ks = 0; ks < 4; ++ks) {
            int k = ks * 32 + l4 * 8;
            half8_t a[2], b[2];
#pragma unroll
            for (int mi = 0; mi < 2; ++mi)
                a[mi] = lds_read8(sT, wm * 32 + mi * 16 + l15, 256, k);
#pragma unroll
            for (int ni = 0; ni < 2; ++ni)
                b[ni] = lds_read8(sB2, wn * 32 + ni * 16 + l15, 256, k);
#pragma unroll
            for (int mi = 0; mi < 2; ++mi)
#pragma unroll
                for (int ni = 0; ni < 2; ++ni)
                    acc2[mi][ni] = __builtin_amdgcn_mfma_f32_16x16x32_f16(
                        a[mi], b[ni], acc2[mi][ni], 0, 0, 0);
        }
        __syncthreads();

        float bias2[2];
        int gcol[2];
#pragma unroll
        for (int ni = 0; ni < 2; ++ni) {
            gcol[ni] = wn * 32 + ni * 16 + l15;
            bias2[ni] = fb2[gcol[ni]];
        }
#pragma unroll
        for (int mi = 0; mi < 2; ++mi) {
            int ge[4], s4[4], dn4[4];
            float d4[4];
#pragma unroll
            for (int j = 0; j < 4; ++j) {
                int el = wm * 32 + mi * 16 + l4 * 4 + j;
                ge[j] = e0 + el;
                int idx = (ge[j] < E) ? ge[j] : (E - 1);
                s4[j]  = srcp[idx];
                dn4[j] = dstp[idx];
                d4[j]  = edge_weight[idx];
            }
#pragma unroll
            for (int j = 0; j < 4; ++j) {
                if (ge[j] >= E) continue;
                float C = (d4[j] < RC_CUT)
                            ? 0.5f * (__cosf(d4[j] * 0.6283185307179586f) + 1.0f)
                            : 0.0f;
                const _Float16* hrow = h + (size_t)s4[j] * FD;
                float* ar = agg + (size_t)dn4[j] * FD;
#pragma unroll
                for (int ni = 0; ni < 2; ++ni) {
                    int g = gcol[ni];
                    float wv = (acc2[mi][ni][j] + bias2[ni]) * C;
                    atomicAdd(ar + g, wv * (float)hrow[g]);
                }
            }
        }
    }
}

// ---------------- final: disc conv + lin2 + tanh + lin (h f16) --------------
// Runs on BOTH paths, transforming the aggregation in out -> final output.
__global__ __launch_bounds__(256) void final_kernel(
    const float* aggin, const _Float16* __restrict__ h,
    const float* __restrict__ disc_w,
    const float* __restrict__ lin2_w, const float* __restrict__ lin2_b,
    const float* __restrict__ lin_w, const float* __restrict__ lin_b,
    float* out, int n)
{
    __shared__ float sg[16][FD];
    __shared__ float sm[16][FD];
    int base = blockIdx.x * 16;
    for (int i = threadIdx.x; i < 16 * FD; i += 256) {
        int r = i >> 7, c = i & 127;
        int row = base + r;
        float v = 0.0f;
        if (row < n) {
            v = aggin[(size_t)row * FD + c]
              + disc_w[c] * (float)h[(size_t)row * FD + c];
            if (row + 1 < n)
                v += disc_w[FD + c] * (float)h[(size_t)(row + 1) * FD + c];
            if (row >= 1)
                v += disc_w[2 * FD + c] * (float)h[(size_t)(row - 1) * FD + c];
        }
        sg[r][c] = v;
    }
    __syncthreads();
    int f = threadIdx.x & 127;
    int half = threadIdx.x >> 7;
    {
        float acc[8];
        float b = lin2_b[f];
#pragma unroll
        for (int r = 0; r < 8; ++r) acc[r] = b;
        const float* wrow = lin2_w + (size_t)f * FD;
        for (int k = 0; k < FD; k += 4) {
            float4 wv = *(const float4*)(wrow + k);
#pragma unroll
            for (int r = 0; r < 8; ++r) {
                acc[r] += sg[half * 8 + r][k]     * wv.x;
                acc[r] += sg[half * 8 + r][k + 1] * wv.y;
                acc[r] += sg[half * 8 + r][k + 2] * wv.z;
                acc[r] += sg[half * 8 + r][k + 3] * wv.w;
            }
        }
#pragma unroll
        for (int r = 0; r < 8; ++r) sm[half * 8 + r][f] = fast_tanh(acc[r]);
    }
    __syncthreads();
    {
        float acc[8];
        float b = lin_b[f];
#pragma unroll
        for (int r = 0; r < 8; ++r) acc[r] = b;
        const float* wrow = lin_w + (size_t)f * HD;
        for (int k = 0; k < FD; k += 4) {
            float4 wv = *(const float4*)(wrow + k);
#pragma unroll
            for (int r = 0; r < 8; ++r) {
                acc[r] += sm[half * 8 + r][k]     * wv.x;
                acc[r] += sm[half * 8 + r][k + 1] * wv.y;
                acc[r] += sm[half * 8 + r][k + 2] * wv.z;
                acc[r] += sm[half * 8 + r][k + 3] * wv.w;
            }
        }
#pragma unroll
        for (int r = 0; r < 8; ++r) {
            int row = base + half * 8 + r;
            if (row < n) out[(size_t)row * HD + f] = acc[r];
        }
    }
}

extern "C" void kernel_launch(void* const* d_in, const int* in_sizes, int n_in,
                              void* d_out, int out_size, void* d_ws, size_t ws_size,
                              hipStream_t stream)
{
    const float* x      = (const float*)d_in[0];
    const float* ew     = (const float*)d_in[1];
    const float* ea     = (const float*)d_in[2];
    const float* fw1    = (const float*)d_in[3];
    const float* fb1    = (const float*)d_in[4];
    const float* fw2    = (const float*)d_in[5];
    const float* fb2    = (const float*)d_in[6];
    const float* lin1_w = (const float*)d_in[7];
    const float* lin2_w = (const float*)d_in[8];
    const float* lin2_b = (const float*)d_in[9];
    const float* disc_w = (const float*)d_in[10];
    const float* lin_w  = (const float*)d_in[11];
    const float* lin_b  = (const float*)d_in[12];
    const int*   eidx   = (const int*)d_in[13];

    int n = in_sizes[0] / HD;
    int E = in_sizes[1];
    int ntiles = (E + TE - 1) / TE;
    int nb = (n + 255) / 256;
    float* out = (float*)d_out;

    const int* srcp = eidx;
    const int* dstp = eidx + E;

    // workspace layout (16B-aligned sections)
    char* base = (char*)d_ws;
    _Float16*  h    = (_Float16*)base;                    // n*128 f16
    size_t off_h    = (size_t)n * FD * 2;
    _Float16*  Wp   = (_Float16*)(base + off_h);          // E*128 f16
    size_t off_w    = off_h + (size_t)E * FD * 2;
    int*       inv  = (int*)(base + off_w);               // E ints
    size_t off_i    = off_w + (size_t)E * 4;
    unsigned int* meta = (unsigned int*)(base + off_i);   // E u32
    size_t off_m    = off_i + (size_t)E * 4;
    int*       cnt  = (int*)(base + off_m);               // n ints (per-dst)
    int*       offs = cnt + n;                            // n+1 ints
    int*       bsum = offs + n + 1;                       // nb ints
    size_t need     = off_m + (size_t)(2 * n + nb + 16) * 4;

    lin1_kernel<<<(n + 15) / 16, 256, 0, stream>>>(x, lin1_w, h, n);

    size_t smem = 81920;   // 80 KB -> 2 blocks/CU
    if (ws_size >= need && n <= 65535) {
        // ---------- two-phase path: sorted-by-dst, quarter-wave agg ----------
        hipMemsetAsync(cnt, 0, (size_t)n * sizeof(int), stream);
        count_kernel<<<2048, 256, 0, stream>>>(dstp, cnt, E);
        scan1_kernel<<<nb, 256, 0, stream>>>(cnt, bsum, n);
        scan2_kernel<<<1, 64, 0, stream>>>(bsum, nb, offs + n);
        scan3_kernel<<<nb, 256, 0, stream>>>(cnt, bsum, offs, n);
        scatter_kernel<<<2048, 256, 0, stream>>>(srcp, dstp, cnt, inv, meta, E);

        hipFuncSetAttribute((const void*)edge_gemm_kernel,
                            hipFuncAttributeMaxDynamicSharedMemorySize, (int)smem);
        int nblocks = ntiles < 512 ? ntiles : 512;
        edge_gemm_kernel<<<nblocks, 1024, smem, stream>>>(ew, ea, fw1, fb1, fw2, fb2,
                                                          inv, Wp, E, ntiles);

        agg_kernel<<<(n + 3) / 4, 256, 0, stream>>>(Wp, meta, offs, h, out, n);
    } else {
        // ---------- fallback: proven fused atomic kernel ----------
        hipMemsetAsync(d_out, 0, (size_t)out_size * sizeof(float), stream);
        hipFuncSetAttribute((const void*)edge_kernel_atomic,
                            hipFuncAttributeMaxDynamicSharedMemorySize, (int)smem);
        int nblocks = ntiles < 512 ? ntiles : 512;
        edge_kernel_atomic<<<nblocks, 1024, smem, stream>>>(ew, ea, fw1, fb1, fw2, fb2,
                                                            eidx, h, out, E, ntiles);
    }

    final_kernel<<<(n + 15) / 16, 256, 0, stream>>>(out, h, disc_w, lin2_w, lin2_b,
                                                    lin_w, lin_b, out, n);
}